// Round 21
// baseline (77.066 us; speedup 1.0000x reference)
//
#include <hip/hip_runtime.h>
#include <stdint.h>

// Group / KNN: B=16, N=16384, NUM_GROUP=512, GROUP_SIZE=32.
// d_out = neighborhood [16][512][32][3] ++ center [16][512][3] ++ ids [16][512]
//
// r21 = r19 (champion, 67 us) continuing the block-size sweep:
// TB 512->256 gave 73->67 with VALU-busy TIME constant (~43 us) -> fixed
// per-point overhead ~0; group-pair pk-math dominates and is GB-invariant.
// So TB=128 / GB=2 / 4096 blocks = 16 blocks/CU buys occupancy for free.
// r20's explicit pipelining reverted (VGPR 28->44, occupancy -18pt, +2.5%).
// Threshold: per-wave bitonic lane==15 = 16th-smallest lane-min (lane min
// spans 128 pts), T = max over 2 waves -> 32 certified. CAP 320 (looser T).
// Certified superset + exact (key,idx) counting-sort => selection identical
// (absmax canary 0.4521484).

#define TB     128
#define GB     2                  // groups per block
#define PPT    128                // points per thread = 16384/TB
#define NWAVE  (TB / 64)          // 2
#define CAP    320                // per-group candidate capacity

typedef __attribute__((ext_vector_type(2))) float f32x2;

__global__ __launch_bounds__(TB) void group_knn_kernel(
    const float* __restrict__ xyz,   // [16][16384][3]
    float* __restrict__ out_nb,      // [16][512][32][3]
    float* __restrict__ out_ctr,     // [16][512][3]
    float* __restrict__ out_ids)     // [16][512]
{
    const int NPTS = 16384;
    const int GSZ  = 32;

    const int blk = blockIdx.x;            // 0 .. 4095
    const int b   = blk >> 8;              // 256 blocks per batch
    const int g0  = (blk & 255) * GB;      // first group of this block
    const int t   = threadIdx.x;
    const int lane = t & 63;
    const int w    = t >> 6;

    const float* base = xyz + (size_t)b * NPTS * 3;

    // Group-pair constants (block-uniform -> scalar loads).
    f32x2 C0, C1, C2;
    {
        const int ncA = g0 * 32;
        const int ncB = (g0 + 1) * 32;
        C0 = (f32x2){ -2.0f * base[ncA * 3 + 0], -2.0f * base[ncB * 3 + 0] };
        C1 = (f32x2){ -2.0f * base[ncA * 3 + 1], -2.0f * base[ncB * 3 + 1] };
        C2 = (f32x2){ -2.0f * base[ncA * 3 + 2], -2.0f * base[ncB * 3 + 2] };
    }

    __shared__ unsigned long long s_cand[GB][CAP];     // 5120 B
    __shared__ float s_t[GB][NWAVE];
    __shared__ int s_cnt[GB];
    __shared__ unsigned s_win[GB][GSZ];

    // ---- Pass A: per-thread f32x2 min for the group pair ----------------
    f32x2 m2 = (f32x2){ __builtin_inff(), __builtin_inff() };

    for (int i = 0; i < PPT; i += 4) {
        float px[4][3];
#pragma unroll
        for (int u = 0; u < 4; ++u) {              // 4 dwordx3 loads in flight
            const int n = (i + u) * TB + t;
            const float* p = base + (size_t)n * 3;
            px[u][0] = p[0]; px[u][1] = p[1]; px[u][2] = p[2];
        }
#pragma unroll
        for (int u = 0; u < 4; ++u) {
            const float x0 = px[u][0], x1 = px[u][1], x2 = px[u][2];
            const float xs = __builtin_fmaf(x2, x2, __builtin_fmaf(x1, x1, x0 * x0));
            const f32x2 X0 = (f32x2){ x0, x0 };
            const f32x2 X1 = (f32x2){ x1, x1 };
            const f32x2 X2 = (f32x2){ x2, x2 };
            const f32x2 XS = (f32x2){ xs, xs };
            const f32x2 s = C0 * X0 + (C1 * X1 + (C2 * X2 + XS));
            m2 = __builtin_elementwise_min(m2, s);
        }
    }

    // ---- Thresholds: per-wave float bitonic; T = max of 16th-smallest ---
#pragma unroll
    for (int q = 0; q < GB; ++q) {
        float v = (q & 1) ? m2.y : m2.x;
#pragma unroll
        for (int k = 2; k <= 64; k <<= 1) {
#pragma unroll
            for (int j = k >> 1; j > 0; j >>= 1) {
                const float o = __shfl_xor(v, j, 64);
                const bool up = ((lane & k) == 0);
                const bool takeMin = (((lane & j) == 0) == up);
                const float mn = fminf(v, o);
                const float mx = fmaxf(v, o);
                v = takeMin ? mn : mx;
            }
        }
        if (lane == 15) s_t[q][w] = v;   // 16th smallest lane-min in wave
    }
    if (t < GB) s_cnt[t] = 0;
    __syncthreads();                                   // barrier 1

    f32x2 T2;
    {
        float Ta = s_t[0][0], Tb = s_t[1][0];
#pragma unroll
        for (int ww = 1; ww < NWAVE; ++ww) {
            Ta = fmaxf(Ta, s_t[0][ww]);
            Tb = fmaxf(Tb, s_t[1][ww]);
        }
        T2 = (f32x2){ Ta, Tb };
    }

    // ---- Pass B: recompute (L2-hot), collect keys for s <= T_g ----------
    for (int i = 0; i < PPT; i += 4) {
        float px[4][3];
#pragma unroll
        for (int u = 0; u < 4; ++u) {
            const int n = (i + u) * TB + t;
            const float* p = base + (size_t)n * 3;
            px[u][0] = p[0]; px[u][1] = p[1]; px[u][2] = p[2];
        }
#pragma unroll
        for (int u = 0; u < 4; ++u) {
            const int n = (i + u) * TB + t;
            const float x0 = px[u][0], x1 = px[u][1], x2 = px[u][2];
            const float xs = __builtin_fmaf(x2, x2, __builtin_fmaf(x1, x1, x0 * x0));
            const f32x2 X0 = (f32x2){ x0, x0 };
            const f32x2 X1 = (f32x2){ x1, x1 };
            const f32x2 X2 = (f32x2){ x2, x2 };
            const f32x2 XS = (f32x2){ xs, xs };
            const f32x2 s = C0 * X0 + (C1 * X1 + (C2 * X2 + XS));
            if (s.x <= T2.x) {
                unsigned uu = __float_as_uint(s.x);
                uu ^= (unsigned)(((int)uu) >> 31) | 0x80000000u;
                const int pos = atomicAdd(&s_cnt[0], 1);
                if (pos < CAP)
                    s_cand[0][pos] = ((unsigned long long)uu << 32) | (unsigned)n;
            }
            if (s.y <= T2.y) {
                unsigned uu = __float_as_uint(s.y);
                uu ^= (unsigned)(((int)uu) >> 31) | 0x80000000u;
                const int pos = atomicAdd(&s_cnt[1], 1);
                if (pos < CAP)
                    s_cand[1][pos] = ((unsigned long long)uu << 32) | (unsigned)n;
            }
        }
    }
    __syncthreads();                                   // barrier 2

    // ---- Ranking: wave w handles group w (2 waves, 2 groups) ------------
    {
        const int q = w;
        const int cnt = s_cnt[q];
        const float a0 = q ? C0.y : C0.x;
        const float a1 = q ? C1.y : C1.x;
        const float a2 = q ? C2.y : C2.x;
        if (cnt <= CAP) {
            // counting sort (keys unique; broadcast inner reads)
            for (int j = lane; j < cnt; j += 64) {
                const unsigned long long c = s_cand[q][j];
                int r = 0;
                for (int i = 0; i < cnt; ++i) r += (s_cand[q][i] < c) ? 1 : 0;
                if (r < GSZ) s_win[q][r] = (unsigned)c & 0xFFFFu;
            }
        } else {
            // Wave-parallel exact fallback (statistically unreachable).
            unsigned long long last = 0ull;
            for (int k = 0; k < GSZ; ++k) {
                unsigned long long best = ~0ull;
                for (int n = lane; n < NPTS; n += 64) {
                    const float x0 = base[n * 3 + 0];
                    const float x1 = base[n * 3 + 1];
                    const float x2 = base[n * 3 + 2];
                    const float xs = __builtin_fmaf(x2, x2,
                                     __builtin_fmaf(x1, x1, x0 * x0));
                    const float s = __builtin_fmaf(a0, x0,
                                    __builtin_fmaf(a1, x1,
                                    __builtin_fmaf(a2, x2, xs)));
                    unsigned uu = __float_as_uint(s);
                    uu ^= (unsigned)(((int)uu) >> 31) | 0x80000000u;
                    const unsigned long long kk =
                        ((unsigned long long)uu << 32) | (unsigned)n;
                    if ((k == 0 || kk > last) && kk < best) best = kk;
                }
#pragma unroll
                for (int mm = 32; mm >= 1; mm >>= 1) {
                    const unsigned long long o = __shfl_xor(best, mm, 64);
                    best = (o < best) ? o : best;
                }
                last = best;
                if (lane == 0) s_win[q][k] = (unsigned)best & 0xFFFFu;
            }
        }
    }
    __syncthreads();                                   // barrier 3

    // ---- Outputs --------------------------------------------------------
    const int gbase = b * 512 + g0;
    if (t < GB * GSZ) {                       // 64 threads: neighborhoods
        const int q  = t >> 5;
        const int tt = t & 31;
        const int nc = (g0 + q) * 32;
        const float cc0 = base[nc * 3 + 0];
        const float cc1 = base[nc * 3 + 1];
        const float cc2 = base[nc * 3 + 2];
        const unsigned n = s_win[q][tt];
        const float x0 = base[n * 3 + 0];
        const float x1 = base[n * 3 + 1];
        const float x2 = base[n * 3 + 2];
        const size_t ob = (((size_t)(gbase + q)) * GSZ + tt) * 3;
        out_nb[ob + 0] = x0 - cc0;
        out_nb[ob + 1] = x1 - cc1;
        out_nb[ob + 2] = x2 - cc2;
    } else if (t < GB * GSZ + GB * 3) {       // 6 threads: centers
        const int u = t - GB * GSZ;
        const int q = u / 3, c = u % 3;
        out_ctr[(size_t)(gbase + q) * 3 + c] = base[((g0 + q) * 32) * 3 + c];
    } else if (t < GB * GSZ + GB * 3 + GB) {  // 2 threads: ids
        const int q = t - (GB * GSZ + GB * 3);
        out_ids[gbase + q] = (float)((g0 + q) * 32);
    }
}

extern "C" void kernel_launch(void* const* d_in, const int* in_sizes, int n_in,
                              void* d_out, int out_size, void* d_ws, size_t ws_size,
                              hipStream_t stream) {
    const float* xyz = (const float*)d_in[0];
    float* out = (float*)d_out;
    float* out_nb  = out;                        // 786432
    float* out_ctr = out + 786432;               // 24576
    float* out_ids = out + 786432 + 24576;       // 8192
    // 4096 blocks: 16 batches x 256 chunks of 2 groups, 128 threads each.
    hipLaunchKernelGGL(group_knn_kernel, dim3(4096), dim3(TB), 0, stream,
                       xyz, out_nb, out_ctr, out_ids);
}

// Round 22
// 66.631 us; speedup vs baseline: 1.1566x; 1.1566x over previous
//
#include <hip/hip_runtime.h>
#include <stdint.h>

// Group / KNN: B=16, N=16384, NUM_GROUP=512, GROUP_SIZE=32.
// d_out = neighborhood [16][512][32][3] ++ center [16][512][3] ++ ids [16][512]
//
// FINAL (r19 champion, 67 us): GB=4 groups/block, TB=256, 2048 blocks
// (= 8 blocks/CU), direct global dwordx3 reads (no LDS staging — staged
// data has zero reuse and the 3 MB input is L2-resident), packed f32x2
// group-pair distance math, two passes:
//   Pass A: per-thread min per group -> per-wave bitonic of lane minima ->
//           T_g = max over 4 waves of 8th-smallest lane-min (certifies
//           >= 32 distinct points <= T_g).
//   Pass B: recompute (L2-hot), collect exact 64-bit keys
//           (order-transformed score bits << 32 | index) for s <= T_g.
// Ranking: exact counting sort over the candidate superset -> top-32,
// ascending score, ties to lower index. Exact wave-parallel fallback if
// a candidate buffer ever overflows (statistically unreachable, CAP has
// ~4x margin).
//
// Score s = |x|^2 - 2 c.x (rank-equivalent to |x-c|^2 within a group;
// outputs never use the score itself).
//
// Sweep record: TB=512/GB=8 -> 73us, TB=256/GB=4 -> 67us (this),
// TB=128/GB=2 -> 77us. Staging/pipelining/grid/sampling variants all
// regressed (r6-r18, r20-r21). VALU-issue floor ~43us; residual ~24us is
// dependency stall robust to occupancy and pipelining changes.

#define TB     256
#define GB     4                  // groups per block
#define PPT    64                 // points per thread = 16384/TB
#define NWAVE  (TB / 64)          // 4
#define CAP    224                // per-group candidate capacity

typedef __attribute__((ext_vector_type(2))) float f32x2;

__global__ __launch_bounds__(TB) void group_knn_kernel(
    const float* __restrict__ xyz,   // [16][16384][3]
    float* __restrict__ out_nb,      // [16][512][32][3]
    float* __restrict__ out_ctr,     // [16][512][3]
    float* __restrict__ out_ids)     // [16][512]
{
    const int NPTS = 16384;
    const int GSZ  = 32;

    const int blk = blockIdx.x;            // 0 .. 2047
    const int b   = blk >> 7;              // 128 blocks per batch
    const int g0  = (blk & 127) * GB;      // first group of this block
    const int t   = threadIdx.x;
    const int lane = t & 63;
    const int w    = t >> 6;

    const float* base = xyz + (size_t)b * NPTS * 3;

    // Per-group-pair constants (block-uniform -> scalar loads).
    f32x2 C0[2], C1[2], C2[2];
#pragma unroll
    for (int p = 0; p < 2; ++p) {
        const int ncA = (g0 + 2 * p) * 32;
        const int ncB = (g0 + 2 * p + 1) * 32;
        C0[p] = (f32x2){ -2.0f * base[ncA * 3 + 0], -2.0f * base[ncB * 3 + 0] };
        C1[p] = (f32x2){ -2.0f * base[ncA * 3 + 1], -2.0f * base[ncB * 3 + 1] };
        C2[p] = (f32x2){ -2.0f * base[ncA * 3 + 2], -2.0f * base[ncB * 3 + 2] };
    }

    __shared__ unsigned long long s_cand[GB][CAP];     // 7168 B
    __shared__ float s_t[GB][NWAVE];
    __shared__ int s_cnt[GB];
    __shared__ unsigned s_win[GB][GSZ];

    // ---- Pass A: per-thread f32x2 min per group pair --------------------
    f32x2 m2[2];
#pragma unroll
    for (int p = 0; p < 2; ++p)
        m2[p] = (f32x2){ __builtin_inff(), __builtin_inff() };

    for (int i = 0; i < PPT; i += 4) {
        float px[4][3];
#pragma unroll
        for (int u = 0; u < 4; ++u) {              // 4 dwordx3 loads in flight
            const int n = (i + u) * TB + t;
            const float* p = base + (size_t)n * 3;
            px[u][0] = p[0]; px[u][1] = p[1]; px[u][2] = p[2];
        }
#pragma unroll
        for (int u = 0; u < 4; ++u) {
            const float x0 = px[u][0], x1 = px[u][1], x2 = px[u][2];
            const float xs = __builtin_fmaf(x2, x2, __builtin_fmaf(x1, x1, x0 * x0));
            const f32x2 X0 = (f32x2){ x0, x0 };
            const f32x2 X1 = (f32x2){ x1, x1 };
            const f32x2 X2 = (f32x2){ x2, x2 };
            const f32x2 XS = (f32x2){ xs, xs };
#pragma unroll
            for (int p = 0; p < 2; ++p) {
                const f32x2 s = C0[p] * X0 + (C1[p] * X1 + (C2[p] * X2 + XS));
                m2[p] = __builtin_elementwise_min(m2[p], s);
            }
        }
    }

    // ---- Thresholds: per-wave float bitonic; T = max of 8th-smallest ----
#pragma unroll
    for (int q = 0; q < GB; ++q) {
        float v = (q & 1) ? m2[q >> 1].y : m2[q >> 1].x;
#pragma unroll
        for (int k = 2; k <= 64; k <<= 1) {
#pragma unroll
            for (int j = k >> 1; j > 0; j >>= 1) {
                const float o = __shfl_xor(v, j, 64);
                const bool up = ((lane & k) == 0);
                const bool takeMin = (((lane & j) == 0) == up);
                const float mn = fminf(v, o);
                const float mx = fmaxf(v, o);
                v = takeMin ? mn : mx;
            }
        }
        if (lane == 7) s_t[q][w] = v;    // 8th smallest in this wave
    }
    if (t < GB) s_cnt[t] = 0;
    __syncthreads();                                   // barrier 1

    f32x2 T2[2];
#pragma unroll
    for (int p = 0; p < 2; ++p) {
        float Ta = s_t[2 * p][0], Tb = s_t[2 * p + 1][0];
#pragma unroll
        for (int ww = 1; ww < NWAVE; ++ww) {
            Ta = fmaxf(Ta, s_t[2 * p][ww]);
            Tb = fmaxf(Tb, s_t[2 * p + 1][ww]);
        }
        T2[p] = (f32x2){ Ta, Tb };
    }

    // ---- Pass B: recompute (L2-hot), collect keys for s <= T_g ----------
    for (int i = 0; i < PPT; i += 4) {
        float px[4][3];
#pragma unroll
        for (int u = 0; u < 4; ++u) {
            const int n = (i + u) * TB + t;
            const float* p = base + (size_t)n * 3;
            px[u][0] = p[0]; px[u][1] = p[1]; px[u][2] = p[2];
        }
#pragma unroll
        for (int u = 0; u < 4; ++u) {
            const int n = (i + u) * TB + t;
            const float x0 = px[u][0], x1 = px[u][1], x2 = px[u][2];
            const float xs = __builtin_fmaf(x2, x2, __builtin_fmaf(x1, x1, x0 * x0));
            const f32x2 X0 = (f32x2){ x0, x0 };
            const f32x2 X1 = (f32x2){ x1, x1 };
            const f32x2 X2 = (f32x2){ x2, x2 };
            const f32x2 XS = (f32x2){ xs, xs };
#pragma unroll
            for (int p = 0; p < 2; ++p) {
                const f32x2 s = C0[p] * X0 + (C1[p] * X1 + (C2[p] * X2 + XS));
                if (s.x <= T2[p].x) {
                    unsigned uu = __float_as_uint(s.x);
                    uu ^= (unsigned)(((int)uu) >> 31) | 0x80000000u;
                    const int pos = atomicAdd(&s_cnt[2 * p], 1);
                    if (pos < CAP)
                        s_cand[2 * p][pos] = ((unsigned long long)uu << 32) | (unsigned)n;
                }
                if (s.y <= T2[p].y) {
                    unsigned uu = __float_as_uint(s.y);
                    uu ^= (unsigned)(((int)uu) >> 31) | 0x80000000u;
                    const int pos = atomicAdd(&s_cnt[2 * p + 1], 1);
                    if (pos < CAP)
                        s_cand[2 * p + 1][pos] = ((unsigned long long)uu << 32) | (unsigned)n;
                }
            }
        }
    }
    __syncthreads();                                   // barrier 2

    // ---- Ranking: wave w handles group w (4 waves, 4 groups) ------------
    {
        const int q = w;
        const int cnt = s_cnt[q];
        const float a0 = (q & 1) ? C0[q >> 1].y : C0[q >> 1].x;
        const float a1 = (q & 1) ? C1[q >> 1].y : C1[q >> 1].x;
        const float a2 = (q & 1) ? C2[q >> 1].y : C2[q >> 1].x;
        if (cnt <= CAP) {
            // counting sort (keys unique; broadcast inner reads)
            for (int j = lane; j < cnt; j += 64) {
                const unsigned long long c = s_cand[q][j];
                int r = 0;
                for (int i = 0; i < cnt; ++i) r += (s_cand[q][i] < c) ? 1 : 0;
                if (r < GSZ) s_win[q][r] = (unsigned)c & 0xFFFFu;
            }
        } else {
            // Wave-parallel exact fallback (statistically unreachable).
            unsigned long long last = 0ull;
            for (int k = 0; k < GSZ; ++k) {
                unsigned long long best = ~0ull;
                for (int n = lane; n < NPTS; n += 64) {
                    const float x0 = base[n * 3 + 0];
                    const float x1 = base[n * 3 + 1];
                    const float x2 = base[n * 3 + 2];
                    const float xs = __builtin_fmaf(x2, x2,
                                     __builtin_fmaf(x1, x1, x0 * x0));
                    const float s = __builtin_fmaf(a0, x0,
                                    __builtin_fmaf(a1, x1,
                                    __builtin_fmaf(a2, x2, xs)));
                    unsigned uu = __float_as_uint(s);
                    uu ^= (unsigned)(((int)uu) >> 31) | 0x80000000u;
                    const unsigned long long kk =
                        ((unsigned long long)uu << 32) | (unsigned)n;
                    if ((k == 0 || kk > last) && kk < best) best = kk;
                }
#pragma unroll
                for (int mm = 32; mm >= 1; mm >>= 1) {
                    const unsigned long long o = __shfl_xor(best, mm, 64);
                    best = (o < best) ? o : best;
                }
                last = best;
                if (lane == 0) s_win[q][k] = (unsigned)best & 0xFFFFu;
            }
        }
    }
    __syncthreads();                                   // barrier 3

    // ---- Outputs --------------------------------------------------------
    const int gbase = b * 512 + g0;
    if (t < GB * GSZ) {                       // 128 threads: neighborhoods
        const int q  = t >> 5;
        const int tt = t & 31;
        const int nc = (g0 + q) * 32;
        const float cc0 = base[nc * 3 + 0];
        const float cc1 = base[nc * 3 + 1];
        const float cc2 = base[nc * 3 + 2];
        const unsigned n = s_win[q][tt];
        const float x0 = base[n * 3 + 0];
        const float x1 = base[n * 3 + 1];
        const float x2 = base[n * 3 + 2];
        const size_t ob = (((size_t)(gbase + q)) * GSZ + tt) * 3;
        out_nb[ob + 0] = x0 - cc0;
        out_nb[ob + 1] = x1 - cc1;
        out_nb[ob + 2] = x2 - cc2;
    } else if (t < GB * GSZ + GB * 3) {       // 12 threads: centers
        const int u = t - GB * GSZ;
        const int q = u / 3, c = u % 3;
        out_ctr[(size_t)(gbase + q) * 3 + c] = base[((g0 + q) * 32) * 3 + c];
    } else if (t < GB * GSZ + GB * 3 + GB) {  // 4 threads: ids
        const int q = t - (GB * GSZ + GB * 3);
        out_ids[gbase + q] = (float)((g0 + q) * 32);
    }
}

extern "C" void kernel_launch(void* const* d_in, const int* in_sizes, int n_in,
                              void* d_out, int out_size, void* d_ws, size_t ws_size,
                              hipStream_t stream) {
    const float* xyz = (const float*)d_in[0];
    float* out = (float*)d_out;
    float* out_nb  = out;                        // 786432
    float* out_ctr = out + 786432;               // 24576
    float* out_ids = out + 786432 + 24576;       // 8192
    // 2048 blocks: 16 batches x 128 chunks of 4 groups, 256 threads each.
    hipLaunchKernelGGL(group_knn_kernel, dim3(2048), dim3(TB), 0, stream,
                       xyz, out_nb, out_ctr, out_ids);
}